// Round 7
// baseline (230.936 us; speedup 1.0000x reference)
//
#include <hip/hip_runtime.h>
#include <math.h>

// OscillatoryAttention: B=2,S=2048,D=1024,H=16,dk=64. FP32 in/out, bf16 MFMA inside.
// R7 attention: 32x32x16 MFMA (2x FLOP per LDS byte); S^T so P^T C-regs feed PV
// A-frags directly (zero P LDS round-trip; V token order swap23-permuted within
// 16-groups); coherence as rank-2 MFMA channels (Qcs/Kcs, 5th K-chunk) -> no
// cos/sin or per-score VALU in the hot loop. Swizzle rot(row)=(row>>2)&7.

#define S_LEN 2048
#define NHEADS 16

typedef __attribute__((ext_vector_type(8))) short short8;
typedef __attribute__((ext_vector_type(4))) float floatx4;
typedef __attribute__((ext_vector_type(16))) float floatx16;

__device__ inline unsigned short f2bf(float f) {
    union { float f; unsigned int i; } v; v.f = f;
    unsigned int u = v.i;
    return (unsigned short)((u + 0x7fffu + ((u >> 16) & 1u)) >> 16);
}
// pack two f32 -> packed bf16 u32 (truncation), low short = lo
__device__ inline unsigned int pack2_bf16(float hi, float lo) {
    union { float f; unsigned int u; } a, b; a.f = hi; b.f = lo;
    return __builtin_amdgcn_perm(a.u, b.u, 0x07060302u);
}
__device__ inline void async_copy16(const unsigned short* src, unsigned short* dst_lds) {
    __builtin_amdgcn_global_load_lds(
        (const __attribute__((address_space(1))) unsigned int*)(src),
        (__attribute__((address_space(3))) unsigned int*)(dst_lds), 16, 0, 0);
}
__device__ inline floatx16 zero16() {
    floatx16 v;
#pragma unroll
    for (int i = 0; i < 16; i++) v[i] = 0.f;
    return v;
}

// ---------------- prep: phase+cvt (blocks 0..4095) | weight transpose (4096..5119)
// phase part writes Qcs[(b,h,s,16)] = [aL2E*cos, aL2E*sin, 0...] and
// Kcs[(b,h,s,16)] = [cos, sin, 0...] in bf16.
__global__ __launch_bounds__(256) void prep_kernel(
    const float* __restrict__ x, const float* __restrict__ Wp,
    const float* __restrict__ bp, const float* __restrict__ alpha,
    const float* __restrict__ w0, const float* __restrict__ w1,
    const float* __restrict__ w2, const float* __restrict__ w3,
    unsigned short* __restrict__ d0, unsigned short* __restrict__ d1,
    unsigned short* __restrict__ d2, unsigned short* __restrict__ d3,
    unsigned short* __restrict__ qcs, unsigned short* __restrict__ kcs,
    unsigned short* __restrict__ xb) {
    __shared__ __align__(16) unsigned short shmem[64 * 72];
    int t = threadIdx.x;
    if (blockIdx.x < 4096) {
        float* red = reinterpret_cast<float*>(shmem);
        int bid = blockIdx.x;
        int b = bid >> 11, s = bid & 2047;
        int h = t & 15, c = t >> 4;
        const float* xr = x + (size_t)bid * 1024;
        {
            float4 xv = *reinterpret_cast<const float4*>(&xr[t * 4]);
            uint2 o;
            o.x = (unsigned int)f2bf(xv.x) | ((unsigned int)f2bf(xv.y) << 16);
            o.y = (unsigned int)f2bf(xv.z) | ((unsigned int)f2bf(xv.w) << 16);
            *reinterpret_cast<uint2*>(&xb[(size_t)bid * 1024 + t * 4]) = o;
        }
        float acc = 0.f;
#pragma unroll 8
        for (int kk = 0; kk < 64; kk++) {
            int k = c * 64 + kk;
            acc += xr[k] * Wp[k * 16 + h];
        }
        red[t] = acc;
        __syncthreads();
        if (t < 16) {
            float sum = 0.f;
#pragma unroll
            for (int c2 = 0; c2 < 16; c2++) sum += red[c2 * 16 + t];
            sum += bp[t];
            float sv, cv;
            __sincosf(sum, &sv, &cv);
            float as = alpha[t] * 1.44269504f;
            size_t off = ((size_t)(b * NHEADS + t) * S_LEN + s) * 16;
            uint4 qv = make_uint4(
                (unsigned int)f2bf(as * cv) | ((unsigned int)f2bf(as * sv) << 16), 0u, 0u, 0u);
            uint4 kv = make_uint4(
                (unsigned int)f2bf(cv) | ((unsigned int)f2bf(sv) << 16), 0u, 0u, 0u);
            uint4 z = make_uint4(0u, 0u, 0u, 0u);
            *reinterpret_cast<uint4*>(&qcs[off]) = qv;
            *reinterpret_cast<uint4*>(&qcs[off + 8]) = z;
            *reinterpret_cast<uint4*>(&kcs[off]) = kv;
            *reinterpret_cast<uint4*>(&kcs[off + 8]) = z;
        }
    } else {
        unsigned short (*tile)[72] = reinterpret_cast<unsigned short (*)[72]>(shmem);
        int bid = blockIdx.x - 4096;
        int mat = bid >> 8;
        int tl  = bid & 255;
        int tr = tl >> 4, tc = tl & 15;
        const float* src    = (mat == 0) ? w0 : (mat == 1) ? w1 : (mat == 2) ? w2 : w3;
        unsigned short* dst = (mat == 0) ? d0 : (mat == 1) ? d1 : (mat == 2) ? d2 : d3;
        int col = t & 63, rbase = (t >> 6) * 16;
#pragma unroll
        for (int i = 0; i < 16; i++) {
            int row = rbase + i;
            tile[row][col] = f2bf(src[(size_t)(tr * 64 + row) * 1024 + tc * 64 + col]);
        }
        __syncthreads();
#pragma unroll
        for (int i = 0; i < 16; i++) {
            int row = rbase + i;
            dst[(size_t)(tc * 64 + row) * 1024 + tr * 64 + col] = tile[col][row];
        }
    }
}

// ---------------- GEMM (m97 recipe) ---------------------------------------------
// mode 0: row-major fp32 out (+bias) -> of
// mode 1: N=3072 QKV: Q scaled 0.125*log2e -> (B,H,S,dk); K -> (B,H,S,dk);
//         V -> (B,H,dk,S) transposed, token order swap23-permuted within 16-groups.
template <int MT>
__global__ __launch_bounds__(256) void gemm_bt(
    const unsigned short* __restrict__ A, const unsigned short* __restrict__ BT,
    int N, int mode,
    const float* __restrict__ b0, const float* __restrict__ b1,
    const float* __restrict__ b2,
    unsigned short* __restrict__ o0, unsigned short* __restrict__ o1,
    unsigned short* __restrict__ o2, float* __restrict__ of) {
    __shared__ __align__(16) unsigned short As[MT * 32];
    __shared__ __align__(16) unsigned short Bs[128 * 32];
    const int K = 1024;
    const int MI = MT / 32;
    int t = threadIdx.x;
    int mBase = blockIdx.x * MT;
    int nBase = blockIdx.y * 128;
    int w = t >> 6, lane = t & 63, l15 = lane & 15, quad = lane >> 4;
    int wm = (w & 1) * (MT / 2), wn = (w >> 1) * 64;
    floatx4 acc[MI][4];
#pragma unroll
    for (int i = 0; i < MI; i++)
#pragma unroll
        for (int j = 0; j < 4; j++) acc[i][j] = (floatx4){0.f, 0.f, 0.f, 0.f};

    int arow = t >> 2, aseg = (t & 3) * 8;
    for (int k0 = 0; k0 < K; k0 += 32) {
        __syncthreads();
#pragma unroll
        for (int i = 0; i < MT / 64; i++)
            async_copy16(&A[(size_t)(mBase + i * 64 + arow) * K + k0 + aseg],
                         &As[(i * 64 + arow) * 32 + aseg]);
#pragma unroll
        for (int i = 0; i < 2; i++)
            async_copy16(&BT[(size_t)(nBase + i * 64 + arow) * K + k0 + aseg],
                         &Bs[(i * 64 + arow) * 32 + aseg]);
        __syncthreads();
        short8 af[MI], bfr[4];
#pragma unroll
        for (int mi = 0; mi < MI; mi++)
            af[mi] = *reinterpret_cast<const short8*>(&As[(wm + mi * 16 + l15) * 32 + quad * 8]);
#pragma unroll
        for (int ni = 0; ni < 4; ni++)
            bfr[ni] = *reinterpret_cast<const short8*>(&Bs[(wn + ni * 16 + l15) * 32 + quad * 8]);
#pragma unroll
        for (int mi = 0; mi < MI; mi++)
#pragma unroll
            for (int ni = 0; ni < 4; ni++)
                acc[mi][ni] = __builtin_amdgcn_mfma_f32_16x16x32_bf16(af[mi], bfr[ni], acc[mi][ni], 0, 0, 0);
    }

#pragma unroll
    for (int mi = 0; mi < MI; mi++) {
        int rowB = mBase + wm + mi * 16 + quad * 4;
#pragma unroll
        for (int ni = 0; ni < 4; ni++) {
            int col = nBase + wn + ni * 16 + l15;
            if (mode == 0) {
                float bias = b0[col];
#pragma unroll
                for (int r = 0; r < 4; r++) {
                    of[(size_t)(rowB + r) * N + col] = acc[mi][ni][r] + bias;
                }
            } else {
                int mat = col >> 10, nn = col & 1023;
                int h = nn >> 6, d = nn & 63;
                int b = rowB >> 11, sidx = rowB & 2047;
                if (mat == 2) {
                    float bv = b2[nn];
                    unsigned int lo = (unsigned int)f2bf(acc[mi][ni][0] + bv) |
                                      ((unsigned int)f2bf(acc[mi][ni][1] + bv) << 16);
                    unsigned int hi = (unsigned int)f2bf(acc[mi][ni][2] + bv) |
                                      ((unsigned int)f2bf(acc[mi][ni][3] + bv) << 16);
                    int jj = sidx & 15;                     // multiple of 4
                    int s23 = ((jj & 4) << 1) | ((jj & 8) >> 1);  // swap bits 2<->3
                    size_t rowOff = ((size_t)((b * NHEADS + h) * 64 + d)) * S_LEN +
                                    (sidx & ~15) + s23;
                    *reinterpret_cast<uint2*>(&o2[rowOff]) = make_uint2(lo, hi);
                } else {
                    const float* bias  = (mat == 0) ? b0 : b1;
                    unsigned short* op = (mat == 0) ? o0 : o1;
                    float bv = bias[nn];
                    float scl = (mat == 0) ? 0.18033688f : 1.0f;  // dk^-0.5 * log2e
#pragma unroll
                    for (int r = 0; r < 4; r++) {
                        float cv = (acc[mi][ni][r] + bv) * scl;
                        op[(((size_t)b * NHEADS + h) * S_LEN + (sidx + r)) * 64 + d] = f2bf(cv);
                    }
                }
            }
        }
    }
}

// ---------------- flash attention, oscillatory coherence ------------------------
// grid = B*H*(S/128) = 512 blocks, 256 thr (4 waves x 32 Q-cols).
// S^T(j,i) via mfma_32x32x16 (A=Kext rows j, B=Qext cols i); P^T = exp2(S^T) in
// C-layout; C-regs [8h..8h+8) of tile jt == PV A-frag chunk c=2jt+h (V rows are
// swap23-permuted tokens). l via B=ones MFMA. LDS rows rotated (row>>2)&7.
__global__ __launch_bounds__(256) void attn_kernel(
    const unsigned short* __restrict__ Qg, const unsigned short* __restrict__ Qcs,
    const unsigned short* __restrict__ Kg, const unsigned short* __restrict__ Kcs,
    const unsigned short* __restrict__ VTg, unsigned short* __restrict__ ctx) {
    __shared__ __align__(16) unsigned short KdB[2][4096];  // 64 j x 64 dims (swizzled)
    __shared__ __align__(16) unsigned short KcB[2][1024];  // 64 j x 16 coh-dims
    __shared__ __align__(16) unsigned short VtB[2][4096];  // 64 d x 64 tok' (swizzled)

    int bid = blockIdx.x;
    int bh = bid >> 4, qt = bid & 15;
    int t = threadIdx.x, lane = t & 63, w = t >> 6;
    int l31 = lane & 31, g = lane >> 5;
    int i0w = qt * 128 + w * 32;
    size_t base = (size_t)bh * (S_LEN * 64);
    size_t basec = (size_t)bh * (S_LEN * 16);

    // Q B-frags (registers): B[k=dim][n=i], lane n=l31, k=16f+8g+jj
    short8 qd[4], qc;
    {
        const unsigned short* qrow = Qg + base + (size_t)(i0w + l31) * 64;
#pragma unroll
        for (int f = 0; f < 4; f++)
            qd[f] = *reinterpret_cast<const short8*>(qrow + f * 16 + g * 8);
        qc = *reinterpret_cast<const short8*>(Qcs + basec + (size_t)(i0w + l31) * 16 + g * 8);
    }

    // staging geometry: slot t covers LDS bytes 16t (row srow) and +4096 (row srow+32)
    int srow = t >> 3;
    int scol = (((t & 7) - ((srow >> 2) & 7)) & 7) * 8;   // shorts (inverse rotation)
    const unsigned short* kd0 = Kg + base + (size_t)srow * 64 + scol;
    const unsigned short* kd1 = Kg + base + (size_t)(srow + 32) * 64 + scol;
    const unsigned short* vv0 = VTg + base + (size_t)srow * S_LEN + scol;
    const unsigned short* vv1 = VTg + base + (size_t)(srow + 32) * S_LEN + scol;
    const unsigned short* kcc = Kcs + basec + t * 8;

    // stage kt=0 -> buf 0
    async_copy16(kd0, &KdB[0][t * 8]);
    async_copy16(kd1, &KdB[0][2048 + t * 8]);
    async_copy16(vv0, &VtB[0][t * 8]);
    async_copy16(vv1, &VtB[0][2048 + t * 8]);
    if (t < 128) async_copy16(kcc, &KcB[0][t * 8]);

    floatx16 o0 = zero16(), o1 = zero16(), lac = zero16();
    const short8 ones8 = {(short)0x3F80, (short)0x3F80, (short)0x3F80, (short)0x3F80,
                          (short)0x3F80, (short)0x3F80, (short)0x3F80, (short)0x3F80};

    // frag-read rotation: rot(row)= (row>>2)&7; rows used are jt*32+l31 -> rot=(l31>>2)&7
    int rot = (l31 >> 2) & 7;
    int fo[4];
#pragma unroll
    for (int f = 0; f < 4; f++) fo[f] = ((2 * f + g + rot) & 7) * 8;
    int arow = l31 * 64;
    int kcof = l31 * 16 + g * 8;

    for (int kt = 0; kt < 32; kt++) {
        int p = kt & 1;
        __syncthreads();   // drains async copies for kt; buf p^1 free
        if (kt < 31) {
            int kn = kt + 1, pn = p ^ 1;
            async_copy16(kd0 + kn * 4096, &KdB[pn][t * 8]);
            async_copy16(kd1 + kn * 4096, &KdB[pn][2048 + t * 8]);
            async_copy16(vv0 + kn * 64, &VtB[pn][t * 8]);
            async_copy16(vv1 + kn * 64, &VtB[pn][2048 + t * 8]);
            if (t < 128) async_copy16(kcc + kn * 1024, &KcB[pn][t * 8]);
        }

        // S^T per jt tile; exp2 -> PV A-frags pf[c]
        short8 pf[4];
#pragma unroll
        for (int jt = 0; jt < 2; jt++) {
            const unsigned short* kb = &KdB[p][jt * 2048 + arow];
            floatx16 st = zero16();
            st = __builtin_amdgcn_mfma_f32_32x32x16_bf16(
                *reinterpret_cast<const short8*>(kb + fo[0]), qd[0], st, 0, 0, 0);
            st = __builtin_amdgcn_mfma_f32_32x32x16_bf16(
                *reinterpret_cast<const short8*>(kb + fo[1]), qd[1], st, 0, 0, 0);
            st = __builtin_amdgcn_mfma_f32_32x32x16_bf16(
                *reinterpret_cast<const short8*>(kb + fo[2]), qd[2], st, 0, 0, 0);
            st = __builtin_amdgcn_mfma_f32_32x32x16_bf16(
                *reinterpret_cast<const short8*>(kb + fo[3]), qd[3], st, 0, 0, 0);
            st = __builtin_amdgcn_mfma_f32_32x32x16_bf16(
                *reinterpret_cast<const short8*>(&KcB[p][jt * 512 + kcof]), qc, st, 0, 0, 0);
            float pe[16];
#pragma unroll
            for (int r = 0; r < 16; r++) pe[r] = __builtin_amdgcn_exp2f(st[r]);
#pragma unroll
            for (int h = 0; h < 2; h++) {
                union { unsigned int u[4]; short8 s; } pk;
                pk.u[0] = pack2_bf16(pe[8 * h + 1], pe[8 * h + 0]);
                pk.u[1] = pack2_bf16(pe[8 * h + 3], pe[8 * h + 2]);
                pk.u[2] = pack2_bf16(pe[8 * h + 5], pe[8 * h + 4]);
                pk.u[3] = pack2_bf16(pe[8 * h + 7], pe[8 * h + 6]);
                pf[2 * jt + h] = pk.s;
            }
        }

        // l += P @ ones ; O += P @ V
#pragma unroll
        for (int c = 0; c < 4; c++) {
            lac = __builtin_amdgcn_mfma_f32_32x32x16_bf16(pf[c], ones8, lac, 0, 0, 0);
            int vo = ((2 * c + g + rot) & 7) * 8;
            short8 vf0 = *reinterpret_cast<const short8*>(&VtB[p][arow + vo]);
            short8 vf1 = *reinterpret_cast<const short8*>(&VtB[p][2048 + arow + vo]);
            o0 = __builtin_amdgcn_mfma_f32_32x32x16_bf16(pf[c], vf0, o0, 0, 0, 0);
            o1 = __builtin_amdgcn_mfma_f32_32x32x16_bf16(pf[c], vf1, o1, 0, 0, 0);
        }
    }

    // epilogue: i = i0w + (r&3)+8*(r>>2)+4g ; cols d = dt*32 + l31
    int b = bh >> 4, h = bh & 15;
#pragma unroll
    for (int r = 0; r < 16; r++) {
        int i = i0w + (r & 3) + 8 * (r >> 2) + 4 * g;
        float inv = 1.0f / lac[r];
        size_t off = ((size_t)(b * S_LEN + i)) * 1024 + h * 64;
        ctx[off + l31]      = f2bf(o0[r] * inv);
        ctx[off + 32 + l31] = f2bf(o1[r] * inv);
    }
}

extern "C" void kernel_launch(void* const* d_in, const int* in_sizes, int n_in,
                              void* d_out, int out_size, void* d_ws, size_t ws_size,
                              hipStream_t stream) {
    const float* x     = (const float*)d_in[0];
    const float* Wq    = (const float*)d_in[1];
    const float* bq    = (const float*)d_in[2];
    const float* Wk    = (const float*)d_in[3];
    const float* bk    = (const float*)d_in[4];
    const float* Wv    = (const float*)d_in[5];
    const float* bv    = (const float*)d_in[6];
    const float* Wo    = (const float*)d_in[7];
    const float* bo    = (const float*)d_in[8];
    const float* Wp    = (const float*)d_in[9];
    const float* bp    = (const float*)d_in[10];
    const float* alpha = (const float*)d_in[11];
    float* out = (float*)d_out;

    const size_t MB = 1048576;
    char* ws = (char*)d_ws;
    unsigned short* WT   = (unsigned short*)(ws);             // 3072x1024 bf16
    unsigned short* WoT  = (unsigned short*)(ws + 6 * MB);    // 1024x1024 bf16
    unsigned short* xb   = (unsigned short*)(ws + 8 * MB);    // (B,S,D) bf16
    unsigned short* ctx  = (unsigned short*)(ws + 8 * MB);    // aliases xb
    unsigned short* Qw   = (unsigned short*)(ws + 16 * MB);   // (B,H,S,64) pre-scaled
    unsigned short* Kw   = (unsigned short*)(ws + 24 * MB);   // (B,H,S,64)
    unsigned short* VTg  = (unsigned short*)(ws + 32 * MB);   // (B,H,64,S) swap23-perm
    unsigned short* Qcs  = (unsigned short*)(ws + 40 * MB);   // (B,H,S,16) coh channels
    unsigned short* Kcs  = (unsigned short*)(ws + 42 * MB);   // (B,H,S,16)

    prep_kernel<<<dim3(5120), dim3(256), 0, stream>>>(
        x, Wp, bp, alpha, Wq, Wk, Wv, Wo,
        WT, WT + 1048576, WT + 2097152, WoT, Qcs, Kcs, xb);
    gemm_bt<128><<<dim3(32, 24), dim3(256), 0, stream>>>(
        xb, WT, 3072, 1, bq, bk, bv, Qw, Kw, VTg, (float*)nullptr);
    attn_kernel<<<dim3(512), dim3(256), 0, stream>>>(
        Qw, Qcs, Kw, Kcs, VTg, ctx);
    gemm_bt<64><<<dim3(64, 8), dim3(256), 0, stream>>>(
        ctx, WoT, 1024, 0, bo, bo, bo,
        (unsigned short*)nullptr, (unsigned short*)nullptr,
        (unsigned short*)nullptr, out);
}

// Round 8
// 224.330 us; speedup vs baseline: 1.0294x; 1.0294x over previous
//
#include <hip/hip_runtime.h>
#include <math.h>

// OscillatoryAttention: B=2,S=2048,D=1024,H=16,dk=64. FP32 in/out, bf16 MFMA inside.
// R8: (a) GEMMs: BK=64 (32 MFMA/barrier) + XOR swizzle rot=row&7 on 128B rows ->
//     2-way (free) bank access on all b128 frag reads, staging stays contiguous
//     for global_load_lds. (b) attention: split-KV halves across 8 waves (512 thr,
//     72KB LDS, 2 blocks/CU = 50% occupancy cap), fp32 partial combine via LDS.

#define S_LEN 2048
#define NHEADS 16

typedef __attribute__((ext_vector_type(8))) short short8;
typedef __attribute__((ext_vector_type(4))) float floatx4;
typedef __attribute__((ext_vector_type(16))) float floatx16;

__device__ inline unsigned short f2bf(float f) {
    union { float f; unsigned int i; } v; v.f = f;
    unsigned int u = v.i;
    return (unsigned short)((u + 0x7fffu + ((u >> 16) & 1u)) >> 16);
}
__device__ inline unsigned int pack2_bf16(float hi, float lo) {
    union { float f; unsigned int u; } a, b; a.f = hi; b.f = lo;
    return __builtin_amdgcn_perm(a.u, b.u, 0x07060302u);
}
__device__ inline void async_copy16(const unsigned short* src, unsigned short* dst_lds) {
    __builtin_amdgcn_global_load_lds(
        (const __attribute__((address_space(1))) unsigned int*)(src),
        (__attribute__((address_space(3))) unsigned int*)(dst_lds), 16, 0, 0);
}
__device__ inline floatx16 zero16() {
    floatx16 v;
#pragma unroll
    for (int i = 0; i < 16; i++) v[i] = 0.f;
    return v;
}

// ---------------- prep: phase+cvt (blocks 0..4095) | weight transpose (4096..5119)
__global__ __launch_bounds__(256) void prep_kernel(
    const float* __restrict__ x, const float* __restrict__ Wp,
    const float* __restrict__ bp, const float* __restrict__ alpha,
    const float* __restrict__ w0, const float* __restrict__ w1,
    const float* __restrict__ w2, const float* __restrict__ w3,
    unsigned short* __restrict__ d0, unsigned short* __restrict__ d1,
    unsigned short* __restrict__ d2, unsigned short* __restrict__ d3,
    unsigned short* __restrict__ qcs, unsigned short* __restrict__ kcs,
    unsigned short* __restrict__ xb) {
    __shared__ __align__(16) unsigned short shmem[64 * 72];
    int t = threadIdx.x;
    if (blockIdx.x < 4096) {
        float* red = reinterpret_cast<float*>(shmem);
        int bid = blockIdx.x;
        int b = bid >> 11, s = bid & 2047;
        int h = t & 15, c = t >> 4;
        const float* xr = x + (size_t)bid * 1024;
        {
            float4 xv = *reinterpret_cast<const float4*>(&xr[t * 4]);
            uint2 o;
            o.x = (unsigned int)f2bf(xv.x) | ((unsigned int)f2bf(xv.y) << 16);
            o.y = (unsigned int)f2bf(xv.z) | ((unsigned int)f2bf(xv.w) << 16);
            *reinterpret_cast<uint2*>(&xb[(size_t)bid * 1024 + t * 4]) = o;
        }
        float acc = 0.f;
#pragma unroll 8
        for (int kk = 0; kk < 64; kk++) {
            int k = c * 64 + kk;
            acc += xr[k] * Wp[k * 16 + h];
        }
        red[t] = acc;
        __syncthreads();
        if (t < 16) {
            float sum = 0.f;
#pragma unroll
            for (int c2 = 0; c2 < 16; c2++) sum += red[c2 * 16 + t];
            sum += bp[t];
            float sv, cv;
            __sincosf(sum, &sv, &cv);
            float as = alpha[t] * 1.44269504f;
            size_t off = ((size_t)(b * NHEADS + t) * S_LEN + s) * 16;
            uint4 qv = make_uint4(
                (unsigned int)f2bf(as * cv) | ((unsigned int)f2bf(as * sv) << 16), 0u, 0u, 0u);
            uint4 kv = make_uint4(
                (unsigned int)f2bf(cv) | ((unsigned int)f2bf(sv) << 16), 0u, 0u, 0u);
            uint4 z = make_uint4(0u, 0u, 0u, 0u);
            *reinterpret_cast<uint4*>(&qcs[off]) = qv;
            *reinterpret_cast<uint4*>(&qcs[off + 8]) = z;
            *reinterpret_cast<uint4*>(&kcs[off]) = kv;
            *reinterpret_cast<uint4*>(&kcs[off + 8]) = z;
        }
    } else {
        unsigned short (*tile)[72] = reinterpret_cast<unsigned short (*)[72]>(shmem);
        int bid = blockIdx.x - 4096;
        int mat = bid >> 8;
        int tl  = bid & 255;
        int tr = tl >> 4, tc = tl & 15;
        const float* src    = (mat == 0) ? w0 : (mat == 1) ? w1 : (mat == 2) ? w2 : w3;
        unsigned short* dst = (mat == 0) ? d0 : (mat == 1) ? d1 : (mat == 2) ? d2 : d3;
        int col = t & 63, rbase = (t >> 6) * 16;
#pragma unroll
        for (int i = 0; i < 16; i++) {
            int row = rbase + i;
            tile[row][col] = f2bf(src[(size_t)(tr * 64 + row) * 1024 + tc * 64 + col]);
        }
        __syncthreads();
#pragma unroll
        for (int i = 0; i < 16; i++) {
            int row = rbase + i;
            dst[(size_t)(tc * 64 + row) * 1024 + tr * 64 + col] = tile[col][row];
        }
    }
}

// ---------------- GEMM: BK=64, swizzled tiles, global_load_lds ------------------
// mode 0: row-major fp32 out (+bias) -> of
// mode 1: N=3072 QKV: Q scaled 0.125*log2e -> (B,H,S,dk); K -> (B,H,S,dk);
//         V -> (B,H,dk,S) transposed, token order swap23-permuted within 16-groups.
template <int MT>
__global__ __launch_bounds__(256) void gemm_bt(
    const unsigned short* __restrict__ A, const unsigned short* __restrict__ BT,
    int N, int mode,
    const float* __restrict__ b0, const float* __restrict__ b1,
    const float* __restrict__ b2,
    unsigned short* __restrict__ o0, unsigned short* __restrict__ o1,
    unsigned short* __restrict__ o2, float* __restrict__ of) {
    __shared__ __align__(16) unsigned short As[MT * 64];
    __shared__ __align__(16) unsigned short Bs[128 * 64];
    const int K = 1024;
    const int MI = MT / 32;
    int t = threadIdx.x;
    int mBase = blockIdx.x * MT;
    int nBase = blockIdx.y * 128;
    int w = t >> 6, lane = t & 63, l15 = lane & 15, quad = lane >> 4;
    int wm = (w & 1) * (MT / 2), wn = (w >> 1) * 64;
    floatx4 acc[MI][4];
#pragma unroll
    for (int i = 0; i < MI; i++)
#pragma unroll
        for (int j = 0; j < 4; j++) acc[i][j] = (floatx4){0.f, 0.f, 0.f, 0.f};

    // staging: thread t -> LDS granule (t&7) of row (t>>3) (+i*32); swizzled source col
    int srow = t >> 3, sseg = t & 7;
    int scol = ((sseg - (srow & 7)) & 7) * 8;
    int rotf = l15 & 7;   // frag-read rotation

    for (int k0 = 0; k0 < K; k0 += 64) {
        __syncthreads();
#pragma unroll
        for (int i = 0; i < MT / 32; i++)
            async_copy16(&A[(size_t)(mBase + i * 32 + srow) * K + k0 + scol],
                         &As[i * 2048 + t * 8]);
#pragma unroll
        for (int i = 0; i < 4; i++)
            async_copy16(&BT[(size_t)(nBase + i * 32 + srow) * K + k0 + scol],
                         &Bs[i * 2048 + t * 8]);
        __syncthreads();
#pragma unroll
        for (int kk = 0; kk < 2; kk++) {
            int gr = ((kk * 4 + quad + rotf) & 7) * 8;
            short8 af[MI], bfr[4];
#pragma unroll
            for (int mi = 0; mi < MI; mi++)
                af[mi] = *reinterpret_cast<const short8*>(&As[(wm + mi * 16 + l15) * 64 + gr]);
#pragma unroll
            for (int ni = 0; ni < 4; ni++)
                bfr[ni] = *reinterpret_cast<const short8*>(&Bs[(wn + ni * 16 + l15) * 64 + gr]);
#pragma unroll
            for (int mi = 0; mi < MI; mi++)
#pragma unroll
                for (int ni = 0; ni < 4; ni++)
                    acc[mi][ni] = __builtin_amdgcn_mfma_f32_16x16x32_bf16(af[mi], bfr[ni], acc[mi][ni], 0, 0, 0);
        }
    }

#pragma unroll
    for (int mi = 0; mi < MI; mi++) {
        int rowB = mBase + wm + mi * 16 + quad * 4;
#pragma unroll
        for (int ni = 0; ni < 4; ni++) {
            int col = nBase + wn + ni * 16 + l15;
            if (mode == 0) {
                float bias = b0[col];
#pragma unroll
                for (int r = 0; r < 4; r++) {
                    of[(size_t)(rowB + r) * N + col] = acc[mi][ni][r] + bias;
                }
            } else {
                int mat = col >> 10, nn = col & 1023;
                int h = nn >> 6, d = nn & 63;
                int b = rowB >> 11, sidx = rowB & 2047;
                if (mat == 2) {
                    float bv = b2[nn];
                    unsigned int lo = (unsigned int)f2bf(acc[mi][ni][0] + bv) |
                                      ((unsigned int)f2bf(acc[mi][ni][1] + bv) << 16);
                    unsigned int hi = (unsigned int)f2bf(acc[mi][ni][2] + bv) |
                                      ((unsigned int)f2bf(acc[mi][ni][3] + bv) << 16);
                    int jj = sidx & 15;                     // multiple of 4
                    int s23 = ((jj & 4) << 1) | ((jj & 8) >> 1);  // swap bits 2<->3
                    size_t rowOff = ((size_t)((b * NHEADS + h) * 64 + d)) * S_LEN +
                                    (sidx & ~15) + s23;
                    *reinterpret_cast<uint2*>(&o2[rowOff]) = make_uint2(lo, hi);
                } else {
                    const float* bias  = (mat == 0) ? b0 : b1;
                    unsigned short* op = (mat == 0) ? o0 : o1;
                    float bv = bias[nn];
                    float scl = (mat == 0) ? 0.18033688f : 1.0f;  // dk^-0.5 * log2e
#pragma unroll
                    for (int r = 0; r < 4; r++) {
                        float cv = (acc[mi][ni][r] + bv) * scl;
                        op[(((size_t)b * NHEADS + h) * S_LEN + (sidx + r)) * 64 + d] = f2bf(cv);
                    }
                }
            }
        }
    }
}

// ---------------- flash attention, oscillatory coherence ------------------------
// grid = B*H*(S/128) = 512 blocks, 512 thr (8 waves). Waves 0-3: kt 0..15,
// waves 4-7: kt 16..31, separate double-buffered tiles; fp32 partial combine.
// S^T via mfma_32x32x16 (A=K, B=Q); P^T C-regs feed PV A-frags directly; V
// swap23-permuted; coherence = rank-2 MFMA channels. Swizzle rot=row&7.
__global__ __launch_bounds__(512, 4) void attn_kernel(
    const unsigned short* __restrict__ Qg, const unsigned short* __restrict__ Qcs,
    const unsigned short* __restrict__ Kg, const unsigned short* __restrict__ Kcs,
    const unsigned short* __restrict__ VTg, unsigned short* __restrict__ ctx) {
    __shared__ __align__(16) unsigned short smem[36864];   // 72 KB carved manually
    // KD(half,buf) = smem + (half*2+buf)*4096        [0 .. 16384)
    // VT(half,buf) = smem + 16384 + (half*2+buf)*4096 [16384 .. 32768)
    // KC(half,buf) = smem + 32768 + (half*2+buf)*1024 [32768 .. 36864)

    int bid = blockIdx.x;
    int bh = bid >> 4, qt = bid & 15;
    int t = threadIdx.x, lane = t & 63;
    int half = t >> 8, th = t & 255;
    int cg = (t >> 6) & 3;
    int l31 = lane & 31, g = lane >> 5;
    int i0w = qt * 128 + cg * 32;
    size_t base = (size_t)bh * (S_LEN * 64);
    size_t basec = (size_t)bh * (S_LEN * 16);

    // Q B-frags (registers): B[k=dim][n=i]
    short8 qd[4], qc;
    {
        const unsigned short* qrow = Qg + base + (size_t)(i0w + l31) * 64;
#pragma unroll
        for (int f = 0; f < 4; f++)
            qd[f] = *reinterpret_cast<const short8*>(qrow + f * 16 + g * 8);
        qc = *reinterpret_cast<const short8*>(Qcs + basec + (size_t)(i0w + l31) * 16 + g * 8);
    }

    // staging geometry (per half): granule th&7 of rows th>>3 and +32
    int srow = th >> 3, sseg = th & 7;
    int scol = ((sseg - (srow & 7)) & 7) * 8;
    const unsigned short* kd0 = Kg + base + (size_t)srow * 64 + scol;
    const unsigned short* kd1 = Kg + base + (size_t)(srow + 32) * 64 + scol;
    const unsigned short* vv0 = VTg + base + (size_t)srow * S_LEN + scol;
    const unsigned short* vv1 = VTg + base + (size_t)(srow + 32) * S_LEN + scol;
    const unsigned short* kcc = Kcs + basec + th * 8;

    unsigned short* KD0 = smem + (half * 2) * 4096;
    unsigned short* KD1 = smem + (half * 2 + 1) * 4096;
    unsigned short* VT0 = smem + 16384 + (half * 2) * 4096;
    unsigned short* VT1 = smem + 16384 + (half * 2 + 1) * 4096;
    unsigned short* KC0 = smem + 32768 + (half * 2) * 1024;
    unsigned short* KC1 = smem + 32768 + (half * 2 + 1) * 1024;

    int kt0 = half * 16;
    {   // stage it=0
        async_copy16(kd0 + (size_t)kt0 * 4096, KD0 + th * 8);
        async_copy16(kd1 + (size_t)kt0 * 4096, KD0 + 2048 + th * 8);
        async_copy16(vv0 + kt0 * 64, VT0 + th * 8);
        async_copy16(vv1 + kt0 * 64, VT0 + 2048 + th * 8);
        if (th < 128) async_copy16(kcc + (size_t)kt0 * 1024, KC0 + th * 8);
    }

    floatx16 o0 = zero16(), o1 = zero16(), lac = zero16();
    const short8 ones8 = {(short)0x3F80, (short)0x3F80, (short)0x3F80, (short)0x3F80,
                          (short)0x3F80, (short)0x3F80, (short)0x3F80, (short)0x3F80};

    int rot = l31 & 7;
    int kcof = l31 * 16 + g * 8;
    int arow = l31 * 64;

    for (int it = 0; it < 16; it++) {
        int p = it & 1;
        unsigned short* KDp = p ? KD1 : KD0;
        unsigned short* VTp = p ? VT1 : VT0;
        unsigned short* KCp = p ? KC1 : KC0;
        __syncthreads();   // drains async copies for it; other buffer free
        if (it < 15) {
            int kn = kt0 + it + 1;
            unsigned short* KDn = p ? KD0 : KD1;
            unsigned short* VTn = p ? VT0 : VT1;
            unsigned short* KCn = p ? KC0 : KC1;
            async_copy16(kd0 + (size_t)kn * 4096, KDn + th * 8);
            async_copy16(kd1 + (size_t)kn * 4096, KDn + 2048 + th * 8);
            async_copy16(vv0 + kn * 64, VTn + th * 8);
            async_copy16(vv1 + kn * 64, VTn + 2048 + th * 8);
            if (th < 128) async_copy16(kcc + (size_t)kn * 1024, KCn + th * 8);
        }

        short8 pf[4];
#pragma unroll
        for (int jt = 0; jt < 2; jt++) {
            const unsigned short* kb = KDp + jt * 2048 + arow;
            floatx16 st = zero16();
#pragma unroll
            for (int f = 0; f < 4; f++) {
                int fo = ((2 * f + g + rot) & 7) * 8;
                st = __builtin_amdgcn_mfma_f32_32x32x16_bf16(
                    *reinterpret_cast<const short8*>(kb + fo), qd[f], st, 0, 0, 0);
            }
            st = __builtin_amdgcn_mfma_f32_32x32x16_bf16(
                *reinterpret_cast<const short8*>(KCp + jt * 512 + kcof), qc, st, 0, 0, 0);
            float pe[16];
#pragma unroll
            for (int r = 0; r < 16; r++) pe[r] = __builtin_amdgcn_exp2f(st[r]);
#pragma unroll
            for (int h = 0; h < 2; h++) {
                union { unsigned int u[4]; short8 s; } pk;
                pk.u[0] = pack2_bf16(pe[8 * h + 1], pe[8 * h + 0]);
                pk.u[1] = pack2_bf16(pe[8 * h + 3], pe[8 * h + 2]);
                pk.u[2] = pack2_bf16(pe[8 * h + 5], pe[8 * h + 4]);
                pk.u[3] = pack2_bf16(pe[8 * h + 7], pe[8 * h + 6]);
                pf[2 * jt + h] = pk.s;
            }
        }

#pragma unroll
        for (int c = 0; c < 4; c++) {
            lac = __builtin_amdgcn_mfma_f32_32x32x16_bf16(pf[c], ones8, lac, 0, 0, 0);
            int vo = ((2 * c + g + rot) & 7) * 8;
            short8 vf0 = *reinterpret_cast<const short8*>(VTp + arow + vo);
            short8 vf1 = *reinterpret_cast<const short8*>(VTp + 2048 + arow + vo);
            o0 = __builtin_amdgcn_mfma_f32_32x32x16_bf16(pf[c], vf0, o0, 0, 0, 0);
            o1 = __builtin_amdgcn_mfma_f32_32x32x16_bf16(pf[c], vf1, o1, 0, 0, 0);
        }
    }

    // combine halves: [j 0..47][lane-of-cg] fp32 layout (conflict-free b32)
    float* xch = reinterpret_cast<float*>(smem);
    __syncthreads();
    if (half == 1) {
        int xb2 = cg * 3072 + lane;
#pragma unroll
        for (int r = 0; r < 16; r++) {
            xch[xb2 + r * 64]        = o0[r];
            xch[xb2 + (16 + r) * 64] = o1[r];
            xch[xb2 + (32 + r) * 64] = lac[r];
        }
    }
    __syncthreads();
    if (half == 0) {
        int xb2 = cg * 3072 + lane;
#pragma unroll
        for (int r = 0; r < 16; r++) {
            o0[r] += xch[xb2 + r * 64];
            o1[r] += xch[xb2 + (16 + r) * 64];
            lac[r] += xch[xb2 + (32 + r) * 64];
        }
        int b = bh >> 4, h = bh & 15;
#pragma unroll
        for (int r = 0; r < 16; r++) {
            int i = i0w + (r & 3) + 8 * (r >> 2) + 4 * g;
            float inv = 1.0f / lac[r];
            size_t off = ((size_t)(b * S_LEN + i)) * 1024 + h * 64;
            ctx[off + l31]      = f2bf(o0[r] * inv);
            ctx[off + 32 + l31] = f2bf(o1[r] * inv);
        }
    }
}

extern "C" void kernel_launch(void* const* d_in, const int* in_sizes, int n_in,
                              void* d_out, int out_size, void* d_ws, size_t ws_size,
                              hipStream_t stream) {
    const float* x     = (const float*)d_in[0];
    const float* Wq    = (const float*)d_in[1];
    const float* bq    = (const float*)d_in[2];
    const float* Wk    = (const float*)d_in[3];
    const float* bk    = (const float*)d_in[4];
    const float* Wv    = (const float*)d_in[5];
    const float* bv    = (const float*)d_in[6];
    const float* Wo    = (const float*)d_in[7];
    const float* bo    = (const float*)d_in[8];
    const float* Wp    = (const float*)d_in[9];
    const float* bp    = (const float*)d_in[10];
    const float* alpha = (const float*)d_in[11];
    float* out = (float*)d_out;

    const size_t MB = 1048576;
    char* ws = (char*)d_ws;
    unsigned short* WT   = (unsigned short*)(ws);             // 3072x1024 bf16
    unsigned short* WoT  = (unsigned short*)(ws + 6 * MB);    // 1024x1024 bf16
    unsigned short* xb   = (unsigned short*)(ws + 8 * MB);    // (B,S,D) bf16
    unsigned short* ctx  = (unsigned short*)(ws + 8 * MB);    // aliases xb
    unsigned short* Qw   = (unsigned short*)(ws + 16 * MB);   // (B,H,S,64) pre-scaled
    unsigned short* Kw   = (unsigned short*)(ws + 24 * MB);   // (B,H,S,64)
    unsigned short* VTg  = (unsigned short*)(ws + 32 * MB);   // (B,H,64,S) swap23-perm
    unsigned short* Qcs  = (unsigned short*)(ws + 40 * MB);   // (B,H,S,16) coh channels
    unsigned short* Kcs  = (unsigned short*)(ws + 42 * MB);   // (B,H,S,16)

    prep_kernel<<<dim3(5120), dim3(256), 0, stream>>>(
        x, Wp, bp, alpha, Wq, Wk, Wv, Wo,
        WT, WT + 1048576, WT + 2097152, WoT, Qcs, Kcs, xb);
    gemm_bt<128><<<dim3(32, 24), dim3(256), 0, stream>>>(
        xb, WT, 3072, 1, bq, bk, bv, Qw, Kw, VTg, (float*)nullptr);
    attn_kernel<<<dim3(512), dim3(512), 0, stream>>>(
        Qw, Qcs, Kw, Kcs, VTg, ctx);
    gemm_bt<64><<<dim3(64, 8), dim3(256), 0, stream>>>(
        ctx, WoT, 1024, 0, bo, bo, bo,
        (unsigned short*)nullptr, (unsigned short*)nullptr,
        (unsigned short*)nullptr, out);
}